// Round 6
// baseline (642.760 us; speedup 1.0000x reference)
//
#include <hip/hip_runtime.h>
#include <math.h>

// Problem constants: states [N,D] fp32, centers [G,K,D] fp32, gammas [G] fp32
#define N_TOT 65536
#define D_DIM 64
#define G_NUM 4
#define K_NUM 512
#define RB    256          // state rows per block (8 waves: 4 row-groups x 2 col-halves)

typedef __attribute__((ext_vector_type(4))) float  f32x4;
typedef __attribute__((ext_vector_type(8))) short  short8;   // 8 bf16 = 4 VGPR

__device__ __forceinline__ unsigned int f2u(float x)        { return __builtin_bit_cast(unsigned int, x); }
__device__ __forceinline__ float        u2f(unsigned int x) { return __builtin_bit_cast(float, x); }

// fp32 -> bf16 RNE, low 16 bits
__device__ __forceinline__ unsigned int bf_rne(float x) {
    unsigned int u = f2u(x);
    return (u + 0x7FFFu + ((u >> 16) & 1u)) >> 16;
}

// ---------------- prep: fp32 rows -> FRAGMENT-MAJOR split-bf16 + row sumsq ----------------
// Fragment-major layout: frags[tile][row16][h][hl][lane 0..63][16B], where for lane
// l = q*16 + fr: row = tile*rows + row16*16 + fr, elems = 32h + 8q .. +7, hl = hi/lo.
// A wave-load of 1KB at (tile,row16,h,hl) hands lane l exactly its MFMA fragment slice.
// rpt_shift = log2(rows per tile): 8 for states (256-row bands), 7 for centers (128-row tiles).
__global__ void prep_frag_kernel(const float* __restrict__ in,      // [nrows][64]
                                 unsigned char* __restrict__ frags,
                                 float* __restrict__ sq, int nrows, int rpt_shift)
{
    int gtid = blockIdx.x * 256 + threadIdx.x;
    if (gtid >= nrows * 8) return;
    int row = gtid >> 3, c = gtid & 7;
    const float* p = in + (size_t)row * D_DIM + 8 * c;
    float4 v0 = *(const float4*)p;
    float4 v1 = *(const float4*)(p + 4);
    float vs[8] = {v0.x, v0.y, v0.z, v0.w, v1.x, v1.y, v1.z, v1.w};
    unsigned hi[4], lo[4];
    float s = 0.f;
    #pragma unroll
    for (int i = 0; i < 4; ++i) {
        float a = vs[2 * i], b = vs[2 * i + 1];
        s += a * a + b * b;
        unsigned ha = f2u(a) & 0xFFFF0000u, hb = f2u(b) & 0xFFFF0000u;  // hi = truncate
        hi[i] = (ha >> 16) | hb;
        lo[i] = bf_rne(a - u2f(ha)) | (bf_rne(b - u2f(hb)) << 16);      // lo = RNE(residual)
    }
    const int tile  = row >> rpt_shift;
    const int rin   = row & ((1 << rpt_shift) - 1);
    const int row16 = rin >> 4;
    const int fr    = row & 15;
    const int q     = c & 3;
    const int h     = c >> 2;
    const int r16s  = 1 << (rpt_shift - 4);          // row16s per tile
    unsigned char* base = frags
        + ((((size_t)tile * r16s + row16) * 2 + h) * 2) * 1024   // hl=0 plane
        + (size_t)(q * 16 + fr) * 16;
    *(uint4*)(base)        = make_uint4(hi[0], hi[1], hi[2], hi[3]);
    *(uint4*)(base + 1024) = make_uint4(lo[0], lo[1], lo[2], lo[3]);
    s += __shfl_xor(s, 1, 64);
    s += __shfl_xor(s, 2, 64);
    s += __shfl_xor(s, 4, 64);
    if (c == 0) sq[row] = s;
}

// ---------------- main: NO LDS, NO barriers — direct global->reg fragments ----------------
// grid 256 blocks x 512 threads. Per wave: 64 state rows x 64 center cols per tile-iter.
// A-frags (states) loaded once into registers; B-frags (centers, 512KB = L2-resident)
// loaded per iteration. Stores free-flow at HBM write rate; waves never lockstep.
// MFMA: A-operand := centers, B-operand := states => acc quad = 4 consecutive out cols.
__global__ __launch_bounds__(512, 2)
void rbf_mfma4(const unsigned char* __restrict__ Afrag,   // [256 bands][64KB]
               const unsigned char* __restrict__ Bfrag,   // [16 tiles][32KB]
               const float* __restrict__ gammas,
               const float* __restrict__ x2,              // [N]
               const float* __restrict__ c2,              // [G*512]
               float* __restrict__ out)                   // [N, 2048]
{
    const int tid  = threadIdx.x;
    const int lane = tid & 63;
    const int w    = tid >> 6;          // 0..7
    const int wrow = w >> 1;            // 0..3: 64-row group of the 256-row band
    const int wcol = w & 1;             // 0..1: 64-col half of the 128-col tile
    const int fr   = lane & 15;
    const int q    = lane >> 4;
    const int n0   = blockIdx.x * RB;

    // ---- A fragments: load once, keep in registers for the whole kernel ----
    short8 xhi[4][2], xlo[4][2];
    const unsigned char* Ab = Afrag + (size_t)blockIdx.x * 65536;
    #pragma unroll
    for (int ms = 0; ms < 4; ++ms) {
        #pragma unroll
        for (int h = 0; h < 2; ++h) {
            const unsigned char* p = Ab + (((size_t)(wrow * 4 + ms) * 2 + h) * 2) * 1024
                                        + (size_t)lane * 16;
            xhi[ms][h] = *(const short8*)(p);
            xlo[ms][h] = *(const short8*)(p + 1024);
        }
    }

    float x2v[4];
    #pragma unroll
    for (int ms = 0; ms < 4; ++ms)
        x2v[ms] = x2[n0 + wrow * 64 + ms * 16 + fr];

    const float4 gm = *(const float4*)gammas;

    #pragma unroll 1
    for (int t = 0; t < 16; ++t) {
        const int g  = t >> 2;
        const int kt = t & 3;

        f32x4 acc[4][4];
        #pragma unroll
        for (int ms = 0; ms < 4; ++ms)
            #pragma unroll
            for (int ns = 0; ns < 4; ++ns)
                acc[ms][ns] = (f32x4){0.f, 0.f, 0.f, 0.f};

        // ---- per n-subtile: load center frags from L2, 3 split terms x 2 k-halves ----
        #pragma unroll
        for (int ns = 0; ns < 4; ++ns) {
            short8 chi[2], clo[2];
            #pragma unroll
            for (int h = 0; h < 2; ++h) {
                const unsigned char* p = Bfrag
                    + ((((size_t)t * 8 + wcol * 4 + ns) * 2 + h) * 2) * 1024
                    + (size_t)lane * 16;
                chi[h] = *(const short8*)(p);
                clo[h] = *(const short8*)(p + 1024);
            }
            #pragma unroll
            for (int ms = 0; ms < 4; ++ms) {
                #pragma unroll
                for (int h = 0; h < 2; ++h) {
                    acc[ms][ns] = __builtin_amdgcn_mfma_f32_16x16x32_bf16(chi[h], xhi[ms][h], acc[ms][ns], 0, 0, 0);
                    acc[ms][ns] = __builtin_amdgcn_mfma_f32_16x16x32_bf16(chi[h], xlo[ms][h], acc[ms][ns], 0, 0, 0);
                    acc[ms][ns] = __builtin_amdgcn_mfma_f32_16x16x32_bf16(clo[h], xhi[ms][h], acc[ms][ns], 0, 0, 0);
                }
            }
        }

        // ---- epilogue: d2 = x2 + c2 - 2*dot, clamp, exp(-gamma*d2), dwordx4 stores ----
        const float gamma = (g == 0) ? gm.x : (g == 1) ? gm.y : (g == 2) ? gm.z : gm.w;
        const int   col0  = g * K_NUM + kt * 128 + wcol * 64;

        float c2v[4][4];
        const float* c2g = c2 + col0;
        #pragma unroll
        for (int ns = 0; ns < 4; ++ns) {
            float4 tt = *(const float4*)(c2g + ns * 16 + 4 * q);
            c2v[ns][0] = tt.x; c2v[ns][1] = tt.y; c2v[ns][2] = tt.z; c2v[ns][3] = tt.w;
        }

        #pragma unroll
        for (int ms = 0; ms < 4; ++ms) {
            const int n = n0 + wrow * 64 + ms * 16 + fr;
            const float xv = x2v[ms];
            float* rowp = out + (size_t)n * (G_NUM * K_NUM) + col0;
            #pragma unroll
            for (int ns = 0; ns < 4; ++ns) {
                float4 o;
                o.x = __expf(-gamma * fmaxf(xv + c2v[ns][0] - 2.0f * acc[ms][ns][0], 0.f));
                o.y = __expf(-gamma * fmaxf(xv + c2v[ns][1] - 2.0f * acc[ms][ns][1], 0.f));
                o.z = __expf(-gamma * fmaxf(xv + c2v[ns][2] - 2.0f * acc[ms][ns][2], 0.f));
                o.w = __expf(-gamma * fmaxf(xv + c2v[ns][3] - 2.0f * acc[ms][ns][3], 0.f));
                *(float4*)(rowp + ns * 16 + 4 * q) = o;
            }
        }
    }
}

extern "C" void kernel_launch(void* const* d_in, const int* in_sizes, int n_in,
                              void* d_out, int out_size, void* d_ws, size_t ws_size,
                              hipStream_t stream) {
    const float* states  = (const float*)d_in[0];
    const float* centers = (const float*)d_in[1];
    const float* gammas  = (const float*)d_in[2];
    float* out = (float*)d_out;

    // ws layout: Afrag 16MB | Bfrag 512KB | x2 256KB | c2 8KB
    unsigned char* Afrag = (unsigned char*)d_ws;
    unsigned char* Bfrag = Afrag + (size_t)256 * 65536;          // 16 MB
    float* x2 = (float*)(Bfrag + (size_t)16 * 32768);            // +512 KB
    float* c2 = x2 + N_TOT;                                      // +256 KB

    prep_frag_kernel<<<(N_TOT * 8) / 256, 256, 0, stream>>>(states, Afrag, x2, N_TOT, 8);
    prep_frag_kernel<<<(G_NUM * K_NUM * 8) / 256, 256, 0, stream>>>(centers, Bfrag, c2, G_NUM * K_NUM, 7);

    rbf_mfma4<<<dim3(N_TOT / RB), 512, 0, stream>>>(Afrag, Bfrag, gammas, x2, c2, out);
}